// Round 5
// baseline (354.183 us; speedup 1.0000x reference)
//
#include <hip/hip_runtime.h>

typedef unsigned short u16;
typedef unsigned int u32;
typedef __bf16 bf16x8 __attribute__((ext_vector_type(8)));
typedef float f32x4 __attribute__((ext_vector_type(4)));
typedef u16 u16x8 __attribute__((ext_vector_type(8)));

#define C_DIM 512
#define N_TOK 4096
#define HEADS 8
#define K3 1536

__device__ __forceinline__ u16 f2bf(float f) {
  u32 u = __builtin_bit_cast(u32, f);
  u += 0x7FFFu + ((u >> 16) & 1u);
  return (u16)(u >> 16);
}
__device__ __forceinline__ float bf2f(u16 b) {
  u32 u = ((u32)b) << 16;
  return __builtin_bit_cast(float, u);
}

// w_qkv [1536][512] f32 -> A1 [1536][1536] bf16 cols = [hi | hi | lo]
__global__ void prep_w_kernel(const float* __restrict__ w, u16* __restrict__ A1) {
  int i = blockIdx.x * 256 + threadIdx.x;
  if (i >= 1536 * 512) return;
  int m = i >> 9, c = i & 511;
  float v = w[i];
  u16 hi = f2bf(v);
  u16 lo = f2bf(v - bf2f(hi));
  u16* row = A1 + (size_t)m * K3;
  row[c] = hi; row[512 + c] = hi; row[1024 + c] = lo;
}

// w_out [512][512] f32 -> bf16
__global__ void prep_wout_kernel(const float* __restrict__ w, u16* __restrict__ A2) {
  int i = blockIdx.x * 256 + threadIdx.x;
  if (i >= 512 * 512) return;
  A2[i] = f2bf(w[i]);
}

// x [512][4096] f32 -> B1 [4096][1536] bf16 cols = [xhi | xlo | xhi] (transpose via LDS)
__global__ __launch_bounds__(256) void prep_x_kernel(const float* __restrict__ x, u16* __restrict__ B1) {
  __shared__ float lds[64][65];
  int n0 = blockIdx.x * 64, c0 = blockIdx.y * 64;
  int tid = threadIdx.x;
#pragma unroll
  for (int i = 0; i < 4; i++) {
    int idx = tid + i * 256;
    int r = idx >> 4, s = idx & 15;
    const float4 v = *(const float4*)(x + (size_t)(c0 + r) * N_TOK + n0 + s * 4);
    lds[r][s * 4 + 0] = v.x; lds[r][s * 4 + 1] = v.y;
    lds[r][s * 4 + 2] = v.z; lds[r][s * 4 + 3] = v.w;
  }
  __syncthreads();
  int n = tid >> 2, cs = tid & 3;
  u16x8 hv[2], lv[2];
#pragma unroll
  for (int half = 0; half < 2; half++) {
#pragma unroll
    for (int j = 0; j < 8; j++) {
      float v = lds[cs * 16 + half * 8 + j][n];
      u16 hi = f2bf(v);
      hv[half][j] = hi;
      lv[half][j] = f2bf(v - bf2f(hi));
    }
  }
  u16* row = B1 + (size_t)(n0 + n) * K3 + c0 + cs * 16;
  *(u16x8*)(row) = hv[0];
  *(u16x8*)(row + 8) = hv[1];
  *(u16x8*)(row + 512) = lv[0];
  *(u16x8*)(row + 520) = lv[1];
  *(u16x8*)(row + 1024) = hv[0];
  *(u16x8*)(row + 1032) = hv[1];
}

// NT GEMM: C[m][n] = sum_k A[m][k]*B[n][k]; 128x128 tile, BK=64, 4 waves, swizzled LDS.
__global__ __launch_bounds__(256) void gemm_nt_kernel(
    const u16* __restrict__ A, const u16* __restrict__ B, float* __restrict__ C,
    int M, int N, int K) {
  __shared__ char lds[128 * 64 * 2 * 2];
  char* ldsA = lds;
  char* ldsB = lds + 128 * 64 * 2;
  int n0 = blockIdx.x * 128, m0 = blockIdx.y * 128;
  int tid = threadIdx.x, lane = tid & 63, wid = tid >> 6;
  int wr = wid >> 1, wc = wid & 1;
  f32x4 acc[4][4] = {};
  for (int k0 = 0; k0 < K; k0 += 64) {
    __syncthreads();
#pragma unroll
    for (int i = 0; i < 4; i++) {
      int idx = tid + i * 256;
      int row = idx >> 3, cb = idx & 7;
      uint4 va = *(const uint4*)(A + (size_t)(m0 + row) * K + k0 + cb * 8);
      *(uint4*)(ldsA + row * 128 + ((cb * 16) ^ ((row & 7) << 4))) = va;
      uint4 vb = *(const uint4*)(B + (size_t)(n0 + row) * K + k0 + cb * 8);
      *(uint4*)(ldsB + row * 128 + ((cb * 16) ^ ((row & 7) << 4))) = vb;
    }
    __syncthreads();
#pragma unroll
    for (int kk = 0; kk < 2; kk++) {
      bf16x8 af[4], bfr[4];
#pragma unroll
      for (int mt = 0; mt < 4; mt++) {
        int row = wr * 64 + mt * 16 + (lane & 15);
        int kb = kk * 64 + ((lane >> 4) << 4);
        af[mt] = *(const bf16x8*)(ldsA + row * 128 + (kb ^ ((row & 7) << 4)));
      }
#pragma unroll
      for (int nt = 0; nt < 4; nt++) {
        int row = wc * 64 + nt * 16 + (lane & 15);
        int kb = kk * 64 + ((lane >> 4) << 4);
        bfr[nt] = *(const bf16x8*)(ldsB + row * 128 + (kb ^ ((row & 7) << 4)));
      }
#pragma unroll
      for (int mt = 0; mt < 4; mt++)
#pragma unroll
        for (int nt = 0; nt < 4; nt++)
          acc[mt][nt] = __builtin_amdgcn_mfma_f32_16x16x32_bf16(af[mt], bfr[nt], acc[mt][nt], 0, 0, 0);
    }
  }
#pragma unroll
  for (int mt = 0; mt < 4; mt++)
#pragma unroll
    for (int nt = 0; nt < 4; nt++) {
      int row = m0 + wr * 64 + mt * 16 + ((lane >> 4) << 2);
      int col = n0 + wc * 64 + nt * 16 + (lane & 15);
#pragma unroll
      for (int r = 0; r < 4; r++)
        C[(size_t)(row + r) * N + col] = acc[mt][nt][r];
    }
}

// qkv [4096][1536] f32 -> Qp/Kp [8][4096][128] bf16, both [hi | lo]
__global__ void prep_qk_kernel(const float* __restrict__ qkv, u16* __restrict__ Qp, u16* __restrict__ Kp) {
  int i = blockIdx.x * 256 + threadIdx.x;  // 8*4096*64 = 2097152 exact
  int dh = i & 63;
  int n = (i >> 6) & 4095;
  int h = i >> 18;
  float q = qkv[(size_t)n * K3 + h * 64 + dh];
  float k = qkv[(size_t)n * K3 + 512 + h * 64 + dh];
  u16 qhi = f2bf(q); u16 qlo = f2bf(q - bf2f(qhi));
  u16 khi = f2bf(k); u16 klo = f2bf(k - bf2f(khi));
  u16* qr = Qp + ((size_t)h * N_TOK + n) * 128;
  u16* kr = Kp + ((size_t)h * N_TOK + n) * 128;
  qr[dh] = qhi; qr[64 + dh] = qlo;
  kr[dh] = khi; kr[64 + dh] = klo;
}

// qkv V-part [4096][h*64] -> Vt [8][64][4096] bf16 (V^T per head, via LDS transpose)
__global__ __launch_bounds__(256) void prep_v_kernel(const float* __restrict__ qkv, u16* __restrict__ Vt) {
  __shared__ float lds[64][65];
  int n0 = blockIdx.x * 64, h = blockIdx.y;
  int tid = threadIdx.x;
#pragma unroll
  for (int i = 0; i < 4; i++) {
    int idx = tid + i * 256;
    int r = idx >> 4, s = idx & 15;
    const float4 v = *(const float4*)(qkv + (size_t)(n0 + r) * K3 + 1024 + h * 64 + s * 4);
    lds[r][s * 4 + 0] = v.x; lds[r][s * 4 + 1] = v.y;
    lds[r][s * 4 + 2] = v.z; lds[r][s * 4 + 3] = v.w;
  }
  __syncthreads();
  int dh = tid >> 2, ns = tid & 3;
  u16x8 pv[2];
#pragma unroll
  for (int half = 0; half < 2; half++)
#pragma unroll
    for (int j = 0; j < 8; j++)
      pv[half][j] = f2bf(lds[ns * 16 + half * 8 + j][dh]);
  u16* dst = Vt + ((size_t)h * 64 + dh) * N_TOK + n0 + ns * 16;
  *(u16x8*)(dst) = pv[0];
  *(u16x8*)(dst + 8) = pv[1];
}

// Flash attention v2: double-buffered K/V, register prefetch, 1 barrier/iter.
// Block = (64 q-rows, head), 4 waves x 16 q-rows, kv tiles of 64.
// LDS: K[2] 16KB each @0/16384; V[2] 8KB each @32768/40960; P 8KB @49152.
__global__ __launch_bounds__(256) void attn_kernel(
    const u16* __restrict__ Qp, const u16* __restrict__ Kp,
    const u16* __restrict__ Vt, u16* __restrict__ Obuf) {
  __shared__ char lds[57344];
  int bid = blockIdx.x;
  int h = bid & 7;               // head -> XCD round-robin (L2 locality heuristic)
  int q0 = (bid >> 3) * 64;
  int tid = threadIdx.x, lane = tid & 63, wid = tid >> 6;
  char* myP = lds + 49152 + wid * 2048;

  // Q fragments: Qp row = [qhi(64) | qlo(64)]; chunks q0,q1=hi, q2,q3=lo
  bf16x8 qf[4];
  {
    const u16* qrow = Qp + ((size_t)h * N_TOK + q0 + wid * 16 + (lane & 15)) * 128 + ((lane >> 4) * 8);
#pragma unroll
    for (int c = 0; c < 4; c++) qf[c] = *(const bf16x8*)(qrow + c * 32);
  }
  const u16* Kbase = Kp + (size_t)h * N_TOK * 128;
  const u16* Vbase = Vt + (size_t)h * 64 * N_TOK;

  // stage tile 0 into buffer 0
  {
    uint4 rk[4], rv[2];
#pragma unroll
    for (int i = 0; i < 4; i++) {
      int idx = tid + i * 256, row = idx >> 4, cb = idx & 15;
      rk[i] = *(const uint4*)(Kbase + (size_t)row * 128 + cb * 8);
    }
#pragma unroll
    for (int i = 0; i < 2; i++) {
      int idx = tid + i * 256, row = idx >> 3, cb = idx & 7;
      rv[i] = *(const uint4*)(Vbase + (size_t)row * N_TOK + cb * 8);
    }
#pragma unroll
    for (int i = 0; i < 4; i++) {
      int idx = tid + i * 256, row = idx >> 4, cb = idx & 15;
      *(uint4*)(lds + row * 256 + ((cb * 16) ^ ((row & 7) << 4))) = rk[i];
    }
#pragma unroll
    for (int i = 0; i < 2; i++) {
      int idx = tid + i * 256, row = idx >> 3, cb = idx & 7;
      *(uint4*)(lds + 32768 + row * 128 + ((cb * 16) ^ ((row & 7) << 4))) = rv[i];
    }
  }
  __syncthreads();

  f32x4 o[4] = {};
  float mrow[4], lrow[4];
#pragma unroll
  for (int r = 0; r < 4; r++) { mrow[r] = -INFINITY; lrow[r] = 0.f; }

  for (int t = 0; t < 64; ++t) {
    int cur = t & 1;
    char* kbuf = lds + cur * 16384;
    char* vbuf = lds + 32768 + cur * 8192;
    // prefetch next tile into registers (latency hides under this iter's compute)
    uint4 rk[4], rv[2];
    if (t < 63) {
      int kvn = (t + 1) * 64;
#pragma unroll
      for (int i = 0; i < 4; i++) {
        int idx = tid + i * 256, row = idx >> 4, cb = idx & 15;
        rk[i] = *(const uint4*)(Kbase + (size_t)(kvn + row) * 128 + cb * 8);
      }
#pragma unroll
      for (int i = 0; i < 2; i++) {
        int idx = tid + i * 256, row = idx >> 3, cb = idx & 7;
        rv[i] = *(const uint4*)(Vbase + (size_t)row * N_TOK + kvn + cb * 8);
      }
    }
    // S = (Q.K^T)*8, split precision: qhi*khi + qhi*klo + qlo*khi
    f32x4 s[4];
#pragma unroll
    for (int nt = 0; nt < 4; nt++) {
      int row = nt * 16 + (lane & 15);
      const char* kb = kbuf + row * 256;
      int swz = (row & 7) << 4;
      int ko = (lane >> 4) << 4;
      bf16x8 kf0 = *(const bf16x8*)(kb + ((ko) ^ swz));
      bf16x8 kf1 = *(const bf16x8*)(kb + ((64 + ko) ^ swz));
      bf16x8 kf2 = *(const bf16x8*)(kb + ((128 + ko) ^ swz));
      bf16x8 kf3 = *(const bf16x8*)(kb + ((192 + ko) ^ swz));
      f32x4 acc = {};
      acc = __builtin_amdgcn_mfma_f32_16x16x32_bf16(qf[0], kf0, acc, 0, 0, 0);
      acc = __builtin_amdgcn_mfma_f32_16x16x32_bf16(qf[1], kf1, acc, 0, 0, 0);
      acc = __builtin_amdgcn_mfma_f32_16x16x32_bf16(qf[0], kf2, acc, 0, 0, 0);
      acc = __builtin_amdgcn_mfma_f32_16x16x32_bf16(qf[1], kf3, acc, 0, 0, 0);
      acc = __builtin_amdgcn_mfma_f32_16x16x32_bf16(qf[2], kf0, acc, 0, 0, 0);
      acc = __builtin_amdgcn_mfma_f32_16x16x32_bf16(qf[3], kf1, acc, 0, 0, 0);
      s[nt] = acc * 8.0f;
    }
    // online softmax (rows: (lane>>4)*4+r; cols: nt*16 + (lane&15))
    float pmax[4];
#pragma unroll
    for (int r = 0; r < 4; r++) {
      float m = fmaxf(fmaxf(s[0][r], s[1][r]), fmaxf(s[2][r], s[3][r]));
#pragma unroll
      for (int d = 1; d < 16; d <<= 1) m = fmaxf(m, __shfl_xor(m, d));
      pmax[r] = m;
    }
    float alpha[4];
#pragma unroll
    for (int r = 0; r < 4; r++) {
      float mnew = fmaxf(mrow[r], pmax[r]);
      alpha[r] = __expf(mrow[r] - mnew);
      mrow[r] = mnew;
    }
    float psum[4] = {0.f, 0.f, 0.f, 0.f};
#pragma unroll
    for (int nt = 0; nt < 4; nt++)
#pragma unroll
      for (int r = 0; r < 4; r++) {
        float p = __expf(s[nt][r] - mrow[r]);
        s[nt][r] = p;
        psum[r] += p;
      }
#pragma unroll
    for (int r = 0; r < 4; r++) {
      float t2 = psum[r];
#pragma unroll
      for (int d = 1; d < 16; d <<= 1) t2 += __shfl_xor(t2, d);
      lrow[r] = lrow[r] * alpha[r] + t2;
      o[0][r] *= alpha[r]; o[1][r] *= alpha[r]; o[2][r] *= alpha[r]; o[3][r] *= alpha[r];
    }
    // P -> per-wave LDS scratch (own-wave only: no barrier needed, lgkm ordering)
#pragma unroll
    for (int nt = 0; nt < 4; nt++)
#pragma unroll
      for (int r = 0; r < 4; r++) {
        int prow = ((lane >> 4) << 2) + r;
        int kvb = (nt * 16 + (lane & 15)) * 2;
        *(u16*)(myP + prow * 128 + (kvb ^ ((prow & 7) << 4))) = f2bf(s[nt][r]);
      }
    // O += P . V
#pragma unroll
    for (int c = 0; c < 2; c++) {
      int prow = lane & 15;
      int kb2 = c * 64 + ((lane >> 4) << 4);
      bf16x8 pf = *(const bf16x8*)(myP + prow * 128 + (kb2 ^ ((prow & 7) << 4)));
#pragma unroll
      for (int nt = 0; nt < 4; nt++) {
        int vrow = nt * 16 + (lane & 15);
        bf16x8 vf = *(const bf16x8*)(vbuf + vrow * 128 + (kb2 ^ ((vrow & 7) << 4)));
        o[nt] = __builtin_amdgcn_mfma_f32_16x16x32_bf16(pf, vf, o[nt], 0, 0, 0);
      }
    }
    // publish prefetched tile into back buffer
    if (t < 63) {
      char* kn = lds + (cur ^ 1) * 16384;
      char* vn = lds + 32768 + (cur ^ 1) * 8192;
#pragma unroll
      for (int i = 0; i < 4; i++) {
        int idx = tid + i * 256, row = idx >> 4, cb = idx & 15;
        *(uint4*)(kn + row * 256 + ((cb * 16) ^ ((row & 7) << 4))) = rk[i];
      }
#pragma unroll
      for (int i = 0; i < 2; i++) {
        int idx = tid + i * 256, row = idx >> 3, cb = idx & 7;
        *(uint4*)(vn + row * 128 + ((cb * 16) ^ ((row & 7) << 4))) = rv[i];
      }
    }
    __syncthreads();
  }

  // normalize + write O (bf16, token-major [4096][512]) via per-wave LDS transpose
#pragma unroll
  for (int nt = 0; nt < 4; nt++)
#pragma unroll
    for (int r = 0; r < 4; r++) {
      int row = ((lane >> 4) << 2) + r;
      int colb = (nt * 16 + (lane & 15)) * 2;
      float v = o[nt][r] / lrow[r];
      *(u16*)(myP + row * 128 + (colb ^ ((row & 7) << 4))) = f2bf(v);
    }
  __syncthreads();
  {
    int row = lane >> 2, seg = lane & 3;
#pragma unroll
    for (int half = 0; half < 2; half++) {
      int s16 = seg + half * 4;
      uint4 v = *(const uint4*)(myP + row * 128 + ((s16 * 16) ^ ((row & 7) << 4)));
      *(uint4*)(Obuf + ((size_t)(q0 + wid * 16 + row)) * C_DIM + h * 64 + s16 * 8) = v;
    }
  }
}

extern "C" void kernel_launch(void* const* d_in, const int* in_sizes, int n_in,
                              void* d_out, int out_size, void* d_ws, size_t ws_size,
                              hipStream_t stream) {
  const float* x = (const float*)d_in[0];      // [512][4096]
  const float* w_qkv = (const float*)d_in[1];  // [1536][512]
  const float* w_out = (const float*)d_in[2];  // [512][512]
  float* out = (float*)d_out;                  // [512][4096]
  char* ws = (char*)d_ws;
  // Workspace layout with overlays (total 59,768,832 B <= proven-available).
  // B1/A1 are dead after gemm1: Obuf overlays B1, Vt overlays A1.
  size_t off = 0;
  size_t off_B1 = off;  off += (size_t)N_TOK * K3 * 2;          // 12,582,912
  size_t off_A1 = off;  off += (size_t)K3 * K3 * 2;             //  4,718,592
  size_t off_A2 = off;  off += (size_t)512 * 512 * 2;           //    524,288
  size_t off_qkv = off; off += (size_t)N_TOK * K3 * 4;          // 25,165,824
  size_t off_Qp = off;  off += (size_t)HEADS * N_TOK * 128 * 2; //  8,388,608
  size_t off_Kp = off;  off += (size_t)HEADS * N_TOK * 128 * 2; //  8,388,608
  u16* B1 = (u16*)(ws + off_B1);
  u16* A1 = (u16*)(ws + off_A1);
  u16* A2 = (u16*)(ws + off_A2);
  float* qkv = (float*)(ws + off_qkv);
  u16* Qp = (u16*)(ws + off_Qp);
  u16* Kp = (u16*)(ws + off_Kp);
  u16* Vt = (u16*)(ws + off_A1);    // overlay A1 (4,194,304 <= 4,718,592)
  u16* Obuf = (u16*)(ws + off_B1);  // overlay B1 (4,194,304 <= 12,582,912)

  prep_w_kernel<<<(1536 * 512 + 255) / 256, 256, 0, stream>>>(w_qkv, A1);
  prep_wout_kernel<<<(512 * 512 + 255) / 256, 256, 0, stream>>>(w_out, A2);
  prep_x_kernel<<<dim3(64, 8), 256, 0, stream>>>(x, B1);
  // qkv[token][channel] = sum_k B1[token][k] * A1[channel][k]
  gemm_nt_kernel<<<dim3(K3 / 128, N_TOK / 128), 256, 0, stream>>>(B1, A1, qkv, N_TOK, K3, K3);
  prep_qk_kernel<<<(HEADS * N_TOK * 64) / 256, 256, 0, stream>>>(qkv, Qp, Kp);
  prep_v_kernel<<<dim3(64, 8), 256, 0, stream>>>(qkv, Vt);
  attn_kernel<<<512, 256, 0, stream>>>(Qp, Kp, Vt, Obuf);
  // out[channel][token] = sum_k w_out[channel][k] * Obuf[token][k]
  gemm_nt_kernel<<<dim3(N_TOK / 128, 512 / 128), 256, 0, stream>>>(A2, Obuf, out, 512, N_TOK, 512);
}

// Round 6
// 282.373 us; speedup vs baseline: 1.2543x; 1.2543x over previous
//
#include <hip/hip_runtime.h>

typedef unsigned short u16;
typedef unsigned int u32;
typedef __bf16 bf16x8 __attribute__((ext_vector_type(8)));
typedef float f32x4 __attribute__((ext_vector_type(4)));
typedef u16 u16x8 __attribute__((ext_vector_type(8)));

#define C_DIM 512
#define N_TOK 4096
#define HEADS 8
#define K3 1536

__device__ __forceinline__ u16 f2bf(float f) {
  u32 u = __builtin_bit_cast(u32, f);
  u += 0x7FFFu + ((u >> 16) & 1u);
  return (u16)(u >> 16);
}
__device__ __forceinline__ float bf2f(u16 b) {
  u32 u = ((u32)b) << 16;
  return __builtin_bit_cast(float, u);
}

// w_qkv [1536][512] f32 -> A1 [1536][1536] bf16 cols = [hi | hi | lo]
__global__ void prep_w_kernel(const float* __restrict__ w, u16* __restrict__ A1) {
  int i = blockIdx.x * 256 + threadIdx.x;
  if (i >= 1536 * 512) return;
  int m = i >> 9, c = i & 511;
  float v = w[i];
  u16 hi = f2bf(v);
  u16 lo = f2bf(v - bf2f(hi));
  u16* row = A1 + (size_t)m * K3;
  row[c] = hi; row[512 + c] = hi; row[1024 + c] = lo;
}

// w_out [512][512] f32 -> bf16
__global__ void prep_wout_kernel(const float* __restrict__ w, u16* __restrict__ A2) {
  int i = blockIdx.x * 256 + threadIdx.x;
  if (i >= 512 * 512) return;
  A2[i] = f2bf(w[i]);
}

// x [512][4096] f32 -> B1 [4096][1536] bf16 cols = [xhi | xlo | xhi] (transpose via LDS)
__global__ __launch_bounds__(256) void prep_x_kernel(const float* __restrict__ x, u16* __restrict__ B1) {
  __shared__ float lds[64][65];
  int n0 = blockIdx.x * 64, c0 = blockIdx.y * 64;
  int tid = threadIdx.x;
#pragma unroll
  for (int i = 0; i < 4; i++) {
    int idx = tid + i * 256;
    int r = idx >> 4, s = idx & 15;
    const float4 v = *(const float4*)(x + (size_t)(c0 + r) * N_TOK + n0 + s * 4);
    lds[r][s * 4 + 0] = v.x; lds[r][s * 4 + 1] = v.y;
    lds[r][s * 4 + 2] = v.z; lds[r][s * 4 + 3] = v.w;
  }
  __syncthreads();
  int n = tid >> 2, cs = tid & 3;
  u16x8 hv[2], lv[2];
#pragma unroll
  for (int half = 0; half < 2; half++) {
#pragma unroll
    for (int j = 0; j < 8; j++) {
      float v = lds[cs * 16 + half * 8 + j][n];
      u16 hi = f2bf(v);
      hv[half][j] = hi;
      lv[half][j] = f2bf(v - bf2f(hi));
    }
  }
  u16* row = B1 + (size_t)(n0 + n) * K3 + c0 + cs * 16;
  *(u16x8*)(row) = hv[0];
  *(u16x8*)(row + 8) = hv[1];
  *(u16x8*)(row + 512) = lv[0];
  *(u16x8*)(row + 520) = lv[1];
  *(u16x8*)(row + 1024) = hv[0];
  *(u16x8*)(row + 1032) = hv[1];
}

// NT GEMM: C[m][n] = sum_k A[m][k]*B[n][k]; 128x128 tile, BK=64, 4 waves, swizzled LDS.
__global__ __launch_bounds__(256) void gemm_nt_kernel(
    const u16* __restrict__ A, const u16* __restrict__ B, float* __restrict__ C,
    int M, int N, int K) {
  __shared__ char lds[128 * 64 * 2 * 2];
  char* ldsA = lds;
  char* ldsB = lds + 128 * 64 * 2;
  int n0 = blockIdx.x * 128, m0 = blockIdx.y * 128;
  int tid = threadIdx.x, lane = tid & 63, wid = tid >> 6;
  int wr = wid >> 1, wc = wid & 1;
  f32x4 acc[4][4] = {};
  for (int k0 = 0; k0 < K; k0 += 64) {
    __syncthreads();
#pragma unroll
    for (int i = 0; i < 4; i++) {
      int idx = tid + i * 256;
      int row = idx >> 3, cb = idx & 7;
      uint4 va = *(const uint4*)(A + (size_t)(m0 + row) * K + k0 + cb * 8);
      *(uint4*)(ldsA + row * 128 + ((cb * 16) ^ ((row & 7) << 4))) = va;
      uint4 vb = *(const uint4*)(B + (size_t)(n0 + row) * K + k0 + cb * 8);
      *(uint4*)(ldsB + row * 128 + ((cb * 16) ^ ((row & 7) << 4))) = vb;
    }
    __syncthreads();
#pragma unroll
    for (int kk = 0; kk < 2; kk++) {
      bf16x8 af[4], bfr[4];
#pragma unroll
      for (int mt = 0; mt < 4; mt++) {
        int row = wr * 64 + mt * 16 + (lane & 15);
        int kb = kk * 64 + ((lane >> 4) << 4);
        af[mt] = *(const bf16x8*)(ldsA + row * 128 + (kb ^ ((row & 7) << 4)));
      }
#pragma unroll
      for (int nt = 0; nt < 4; nt++) {
        int row = wc * 64 + nt * 16 + (lane & 15);
        int kb = kk * 64 + ((lane >> 4) << 4);
        bfr[nt] = *(const bf16x8*)(ldsB + row * 128 + (kb ^ ((row & 7) << 4)));
      }
#pragma unroll
      for (int mt = 0; mt < 4; mt++)
#pragma unroll
        for (int nt = 0; nt < 4; nt++)
          acc[mt][nt] = __builtin_amdgcn_mfma_f32_16x16x32_bf16(af[mt], bfr[nt], acc[mt][nt], 0, 0, 0);
    }
  }
#pragma unroll
  for (int mt = 0; mt < 4; mt++)
#pragma unroll
    for (int nt = 0; nt < 4; nt++) {
      int row = m0 + wr * 64 + mt * 16 + ((lane >> 4) << 2);
      int col = n0 + wc * 64 + nt * 16 + (lane & 15);
#pragma unroll
      for (int r = 0; r < 4; r++)
        C[(size_t)(row + r) * N + col] = acc[mt][nt][r];
    }
}

// qkv [4096][1536] f32 -> Qp/Kp [8][4096][128] bf16, both [hi | lo]
__global__ void prep_qk_kernel(const float* __restrict__ qkv, u16* __restrict__ Qp, u16* __restrict__ Kp) {
  int i = blockIdx.x * 256 + threadIdx.x;  // 8*4096*64 = 2097152 exact
  int dh = i & 63;
  int n = (i >> 6) & 4095;
  int h = i >> 18;
  float q = qkv[(size_t)n * K3 + h * 64 + dh];
  float k = qkv[(size_t)n * K3 + 512 + h * 64 + dh];
  u16 qhi = f2bf(q); u16 qlo = f2bf(q - bf2f(qhi));
  u16 khi = f2bf(k); u16 klo = f2bf(k - bf2f(khi));
  u16* qr = Qp + ((size_t)h * N_TOK + n) * 128;
  u16* kr = Kp + ((size_t)h * N_TOK + n) * 128;
  qr[dh] = qhi; qr[64 + dh] = qlo;
  kr[dh] = khi; kr[64 + dh] = klo;
}

// qkv V-part [4096][h*64] -> Vt [8][64][4096] bf16 (V^T per head, via LDS transpose)
__global__ __launch_bounds__(256) void prep_v_kernel(const float* __restrict__ qkv, u16* __restrict__ Vt) {
  __shared__ float lds[64][65];
  int n0 = blockIdx.x * 64, h = blockIdx.y;
  int tid = threadIdx.x;
#pragma unroll
  for (int i = 0; i < 4; i++) {
    int idx = tid + i * 256;
    int r = idx >> 4, s = idx & 15;
    const float4 v = *(const float4*)(qkv + (size_t)(n0 + r) * K3 + 1024 + h * 64 + s * 4);
    lds[r][s * 4 + 0] = v.x; lds[r][s * 4 + 1] = v.y;
    lds[r][s * 4 + 2] = v.z; lds[r][s * 4 + 3] = v.w;
  }
  __syncthreads();
  int dh = tid >> 2, ns = tid & 3;
  u16x8 pv[2];
#pragma unroll
  for (int half = 0; half < 2; half++)
#pragma unroll
    for (int j = 0; j < 8; j++)
      pv[half][j] = f2bf(lds[ns * 16 + half * 8 + j][dh]);
  u16* dst = Vt + ((size_t)h * 64 + dh) * N_TOK + n0 + ns * 16;
  *(u16x8*)(dst) = pv[0];
  *(u16x8*)(dst + 8) = pv[1];
}

// Flash attention, KV-split=2 (round-4 proven inner structure).
// Block = (64 q-rows, head, kv-half); 4 waves x 16 q-rows; 32 kv tiles of 64.
// Emits unnormalized partials: U [half][h][tok][64] f32, M/L [half][h][tok] f32.
// LDS: K 16KB @0; V 8KB @16384; P 8KB @24576. Total 32KB -> 5 blocks/CU by LDS.
__global__ __launch_bounds__(256) void attn_kernel(
    const u16* __restrict__ Qp, const u16* __restrict__ Kp,
    const u16* __restrict__ Vt, float* __restrict__ Uws,
    float* __restrict__ Mws, float* __restrict__ Lws) {
  __shared__ char lds[32768];
  char* ldsK = lds;              // [64 tok][128] bf16 = 256B rows, swizzled
  char* ldsV = lds + 16384;      // [64 dh][64 kv] bf16 = 128B rows, swizzled
  char* ldsP = lds + 24576;      // per-wave [16 q][64 kv] bf16
  int bid = blockIdx.x;
  int h = bid & 7;               // head -> XCD round-robin (confirmed: FETCH 71.7->10.3MB)
  int rest = bid >> 3;           // 0..127
  int half = rest & 1;
  int q0 = (rest >> 1) * 64;
  int kvbase = half * 2048;
  int tid = threadIdx.x, lane = tid & 63, wid = tid >> 6;
  char* myP = ldsP + wid * 2048;

  // Q fragments: row = [qhi(64) | qlo(64)]; qf[0..1]=hi c0,c1; qf[2..3]=lo c0,c1
  bf16x8 qf[4];
  {
    const u16* qrow = Qp + ((size_t)h * N_TOK + q0 + wid * 16 + (lane & 15)) * 128 + ((lane >> 4) * 8);
#pragma unroll
    for (int c = 0; c < 4; c++) qf[c] = *(const bf16x8*)(qrow + c * 32);
  }
  const u16* Kbase = Kp + (size_t)h * N_TOK * 128;
  const u16* Vbase = Vt + (size_t)h * 64 * N_TOK;

  f32x4 o[4] = {};
  float mrow[4], lrow[4];
#pragma unroll
  for (int r = 0; r < 4; r++) { mrow[r] = -INFINITY; lrow[r] = 0.f; }

  for (int t = 0; t < 32; ++t) {
    int kv0 = kvbase + t * 64;
    __syncthreads();  // prior iter's LDS reads done
    // stage K tile: 64 rows x 256B
#pragma unroll
    for (int i = 0; i < 4; i++) {
      int idx = tid + i * 256, row = idx >> 4, cb = idx & 15;
      uint4 v = *(const uint4*)(Kbase + (size_t)(kv0 + row) * 128 + cb * 8);
      *(uint4*)(ldsK + row * 256 + ((cb * 16) ^ ((row & 7) << 4))) = v;
    }
    // stage V tile: 64 rows x 128B
#pragma unroll
    for (int i = 0; i < 2; i++) {
      int idx = tid + i * 256, row = idx >> 3, cb = idx & 7;
      uint4 v = *(const uint4*)(Vbase + (size_t)row * N_TOK + kv0 + cb * 8);
      *(uint4*)(ldsV + row * 128 + ((cb * 16) ^ ((row & 7) << 4))) = v;
    }
    __syncthreads();  // panels ready

    // S = (Q.K^T)*8, split precision: qhi*khi + qhi*klo + qlo*khi
    f32x4 s[4];
#pragma unroll
    for (int nt = 0; nt < 4; nt++) {
      int row = nt * 16 + (lane & 15);
      const char* kb = ldsK + row * 256;
      int swz = (row & 7) << 4;
      int ko = (lane >> 4) << 4;
      bf16x8 kf0 = *(const bf16x8*)(kb + ((ko) ^ swz));
      bf16x8 kf1 = *(const bf16x8*)(kb + ((64 + ko) ^ swz));
      bf16x8 kf2 = *(const bf16x8*)(kb + ((128 + ko) ^ swz));
      bf16x8 kf3 = *(const bf16x8*)(kb + ((192 + ko) ^ swz));
      f32x4 acc = {};
      acc = __builtin_amdgcn_mfma_f32_16x16x32_bf16(qf[0], kf0, acc, 0, 0, 0);
      acc = __builtin_amdgcn_mfma_f32_16x16x32_bf16(qf[1], kf1, acc, 0, 0, 0);
      acc = __builtin_amdgcn_mfma_f32_16x16x32_bf16(qf[0], kf2, acc, 0, 0, 0);
      acc = __builtin_amdgcn_mfma_f32_16x16x32_bf16(qf[1], kf3, acc, 0, 0, 0);
      acc = __builtin_amdgcn_mfma_f32_16x16x32_bf16(qf[2], kf0, acc, 0, 0, 0);
      acc = __builtin_amdgcn_mfma_f32_16x16x32_bf16(qf[3], kf1, acc, 0, 0, 0);
      s[nt] = acc * 8.0f;
    }
    // online softmax (rows: (lane>>4)*4+r; cols: nt*16 + (lane&15))
    float pmax[4];
#pragma unroll
    for (int r = 0; r < 4; r++) {
      float m = fmaxf(fmaxf(s[0][r], s[1][r]), fmaxf(s[2][r], s[3][r]));
#pragma unroll
      for (int d = 1; d < 16; d <<= 1) m = fmaxf(m, __shfl_xor(m, d));
      pmax[r] = m;
    }
    float alpha[4];
#pragma unroll
    for (int r = 0; r < 4; r++) {
      float mnew = fmaxf(mrow[r], pmax[r]);
      alpha[r] = __expf(mrow[r] - mnew);
      mrow[r] = mnew;
    }
    float psum[4] = {0.f, 0.f, 0.f, 0.f};
#pragma unroll
    for (int nt = 0; nt < 4; nt++)
#pragma unroll
      for (int r = 0; r < 4; r++) {
        float p = __expf(s[nt][r] - mrow[r]);
        s[nt][r] = p;
        psum[r] += p;
      }
#pragma unroll
    for (int r = 0; r < 4; r++) {
      float t2 = psum[r];
#pragma unroll
      for (int d = 1; d < 16; d <<= 1) t2 += __shfl_xor(t2, d);
      lrow[r] = lrow[r] * alpha[r] + t2;
      o[0][r] *= alpha[r]; o[1][r] *= alpha[r]; o[2][r] *= alpha[r]; o[3][r] *= alpha[r];
    }
    // P -> per-wave LDS scratch (bf16)
#pragma unroll
    for (int nt = 0; nt < 4; nt++)
#pragma unroll
      for (int r = 0; r < 4; r++) {
        int prow = ((lane >> 4) << 2) + r;
        int kvb = (nt * 16 + (lane & 15)) * 2;
        *(u16*)(myP + prow * 128 + (kvb ^ ((prow & 7) << 4))) = f2bf(s[nt][r]);
      }
    __syncthreads();  // P visible; V still valid
    // O += P . V
#pragma unroll
    for (int c = 0; c < 2; c++) {
      int prow = lane & 15;
      int kb2 = c * 64 + ((lane >> 4) << 4);
      bf16x8 pf = *(const bf16x8*)(myP + prow * 128 + (kb2 ^ ((prow & 7) << 4)));
#pragma unroll
      for (int nt = 0; nt < 4; nt++) {
        int vrow = nt * 16 + (lane & 15);
        bf16x8 vf = *(const bf16x8*)(ldsV + vrow * 128 + (kb2 ^ ((vrow & 7) << 4)));
        o[nt] = __builtin_amdgcn_mfma_f32_16x16x32_bf16(pf, vf, o[nt], 0, 0, 0);
      }
    }
  }

  // epilogue: write unnormalized U (f32) + m, l partials
  size_t base = ((size_t)(half * HEADS + h) * N_TOK);
#pragma unroll
  for (int r = 0; r < 4; r++) {
    int tok = q0 + wid * 16 + ((lane >> 4) << 2) + r;
    float* urow = Uws + (base + tok) * 64;
#pragma unroll
    for (int nt = 0; nt < 4; nt++)
      urow[nt * 16 + (lane & 15)] = o[nt][r];
    if ((lane & 15) == 0) {
      Mws[base + tok] = mrow[r];
      Lws[base + tok] = lrow[r];
    }
  }
}

// Combine the two KV-halves: O = (U1*w1 + U2*w2) / (l1*w1 + l2*w2), w_i = e^{m_i - m}
__global__ void reduce_kernel(const float* __restrict__ Uws, const float* __restrict__ Mws,
                              const float* __restrict__ Lws, u16* __restrict__ Obuf) {
  int i = blockIdx.x * 256 + threadIdx.x;  // 8*4096*16 = 524288 exact
  int d4 = i & 15;
  int tok = (i >> 4) & 4095;
  int h = i >> 16;
  size_t b1 = (size_t)h * N_TOK + tok;
  size_t b2 = (size_t)(HEADS + h) * N_TOK + tok;
  float m1 = Mws[b1], m2 = Mws[b2];
  float l1 = Lws[b1], l2 = Lws[b2];
  float m = fmaxf(m1, m2);
  float w1 = __expf(m1 - m), w2 = __expf(m2 - m);
  float inv = 1.0f / (l1 * w1 + l2 * w2);
  f32x4 u1 = *(const f32x4*)(Uws + b1 * 64 + d4 * 4);
  f32x4 u2 = *(const f32x4*)(Uws + b2 * 64 + d4 * 4);
  u16* dst = Obuf + (size_t)tok * C_DIM + h * 64 + d4 * 4;
#pragma unroll
  for (int j = 0; j < 4; j++)
    dst[j] = f2bf((u1[j] * w1 + u2[j] * w2) * inv);
}

extern "C" void kernel_launch(void* const* d_in, const int* in_sizes, int n_in,
                              void* d_out, int out_size, void* d_ws, size_t ws_size,
                              hipStream_t stream) {
  const float* x = (const float*)d_in[0];      // [512][4096]
  const float* w_qkv = (const float*)d_in[1];  // [1536][512]
  const float* w_out = (const float*)d_in[2];  // [512][512]
  float* out = (float*)d_out;                  // [512][4096]
  char* ws = (char*)d_ws;
  // Workspace (total 59,768,832 B, proven available). Overlays:
  //   Obuf overlays B1 (dead after gemm1); Vt overlays A1 (dead after gemm1);
  //   U/M/L overlay qkv (dead after prep_qk + prep_v): 17,301,504 <= 25,165,824.
  size_t off = 0;
  size_t off_B1 = off;  off += (size_t)N_TOK * K3 * 2;          // 12,582,912
  size_t off_A1 = off;  off += (size_t)K3 * K3 * 2;             //  4,718,592
  size_t off_A2 = off;  off += (size_t)512 * 512 * 2;           //    524,288
  size_t off_qkv = off; off += (size_t)N_TOK * K3 * 4;          // 25,165,824
  size_t off_Qp = off;  off += (size_t)HEADS * N_TOK * 128 * 2; //  8,388,608
  size_t off_Kp = off;  off += (size_t)HEADS * N_TOK * 128 * 2; //  8,388,608
  u16* B1 = (u16*)(ws + off_B1);
  u16* A1 = (u16*)(ws + off_A1);
  u16* A2 = (u16*)(ws + off_A2);
  float* qkv = (float*)(ws + off_qkv);
  u16* Qp = (u16*)(ws + off_Qp);
  u16* Kp = (u16*)(ws + off_Kp);
  u16* Vt = (u16*)(ws + off_A1);     // overlay A1 (4,194,304 <= 4,718,592)
  u16* Obuf = (u16*)(ws + off_B1);   // overlay B1 (4,194,304 <= 12,582,912)
  float* Uws = (float*)(ws + off_qkv);                       // 16,777,216
  float* Mws = (float*)(ws + off_qkv + 16777216);            //    262,144
  float* Lws = (float*)(ws + off_qkv + 16777216 + 262144);   //    262,144

  prep_w_kernel<<<(1536 * 512 + 255) / 256, 256, 0, stream>>>(w_qkv, A1);
  prep_wout_kernel<<<(512 * 512 + 255) / 256, 256, 0, stream>>>(w_out, A2);
  prep_x_kernel<<<dim3(64, 8), 256, 0, stream>>>(x, B1);
  // qkv[token][channel] = sum_k B1[token][k] * A1[channel][k]
  gemm_nt_kernel<<<dim3(K3 / 128, N_TOK / 128), 256, 0, stream>>>(B1, A1, qkv, N_TOK, K3, K3);
  prep_qk_kernel<<<(HEADS * N_TOK * 64) / 256, 256, 0, stream>>>(qkv, Qp, Kp);
  prep_v_kernel<<<dim3(64, 8), 256, 0, stream>>>(qkv, Vt);
  attn_kernel<<<1024, 256, 0, stream>>>(Qp, Kp, Vt, Uws, Mws, Lws);
  reduce_kernel<<<(HEADS * N_TOK * 16) / 256, 256, 0, stream>>>(Uws, Mws, Lws, Obuf);
  // out[channel][token] = sum_k w_out[channel][k] * Obuf[token][k]
  gemm_nt_kernel<<<dim3(N_TOK / 128, 512 / 128), 256, 0, stream>>>(A2, Obuf, out, 512, N_TOK, 512);
}

// Round 8
// 235.516 us; speedup vs baseline: 1.5039x; 1.1990x over previous
//
#include <hip/hip_runtime.h>

typedef unsigned short u16;
typedef unsigned int u32;
typedef unsigned long long u64;
typedef __bf16 bf16x8 __attribute__((ext_vector_type(8)));
typedef float f32x4 __attribute__((ext_vector_type(4)));
typedef u16 u16x8 __attribute__((ext_vector_type(8)));

#define C_DIM 512
#define N_TOK 4096
#define HEADS 8
#define K3 1536
// 8 * log2(e): folds the *8 logit scale and the exp->exp2 conversion into Q.
#define QSCALE 11.5415603071f

__device__ __forceinline__ u16 f2bf(float f) {
  u32 u = __builtin_bit_cast(u32, f);
  u += 0x7FFFu + ((u >> 16) & 1u);
  return (u16)(u >> 16);
}
__device__ __forceinline__ float bf2f(u16 b) {
  u32 u = ((u32)b) << 16;
  return __builtin_bit_cast(float, u);
}

// w_qkv [1536][512] f32 -> A1 [1536][1536] bf16 cols = [hi | hi | lo]
__global__ void prep_w_kernel(const float* __restrict__ w, u16* __restrict__ A1) {
  int i = blockIdx.x * 256 + threadIdx.x;
  if (i >= 1536 * 512) return;
  int m = i >> 9, c = i & 511;
  float v = w[i];
  u16 hi = f2bf(v);
  u16 lo = f2bf(v - bf2f(hi));
  u16* row = A1 + (size_t)m * K3;
  row[c] = hi; row[512 + c] = hi; row[1024 + c] = lo;
}

// w_out [512][512] f32 -> bf16
__global__ void prep_wout_kernel(const float* __restrict__ w, u16* __restrict__ A2) {
  int i = blockIdx.x * 256 + threadIdx.x;
  if (i >= 512 * 512) return;
  A2[i] = f2bf(w[i]);
}

// x [512][4096] f32 -> B1 [4096][1536] bf16 cols = [xhi | xlo | xhi] (transpose via LDS)
__global__ __launch_bounds__(256) void prep_x_kernel(const float* __restrict__ x, u16* __restrict__ B1) {
  __shared__ float lds[64][65];
  int n0 = blockIdx.x * 64, c0 = blockIdx.y * 64;
  int tid = threadIdx.x;
#pragma unroll
  for (int i = 0; i < 4; i++) {
    int idx = tid + i * 256;
    int r = idx >> 4, s = idx & 15;
    const float4 v = *(const float4*)(x + (size_t)(c0 + r) * N_TOK + n0 + s * 4);
    lds[r][s * 4 + 0] = v.x; lds[r][s * 4 + 1] = v.y;
    lds[r][s * 4 + 2] = v.z; lds[r][s * 4 + 3] = v.w;
  }
  __syncthreads();
  int n = tid >> 2, cs = tid & 3;
  u16x8 hv[2], lv[2];
#pragma unroll
  for (int half = 0; half < 2; half++) {
#pragma unroll
    for (int j = 0; j < 8; j++) {
      float v = lds[cs * 16 + half * 8 + j][n];
      u16 hi = f2bf(v);
      hv[half][j] = hi;
      lv[half][j] = f2bf(v - bf2f(hi));
    }
  }
  u16* row = B1 + (size_t)(n0 + n) * K3 + c0 + cs * 16;
  *(u16x8*)(row) = hv[0];
  *(u16x8*)(row + 8) = hv[1];
  *(u16x8*)(row + 512) = lv[0];
  *(u16x8*)(row + 520) = lv[1];
  *(u16x8*)(row + 1024) = hv[0];
  *(u16x8*)(row + 1032) = hv[1];
}

// NT GEMM: C[m][n] = sum_k A[m][k]*B[n][k]; 128x128 tile, BK=64, 4 waves, swizzled LDS.
__global__ __launch_bounds__(256) void gemm_nt_kernel(
    const u16* __restrict__ A, const u16* __restrict__ B, float* __restrict__ C,
    int M, int N, int K) {
  __shared__ char lds[128 * 64 * 2 * 2];
  char* ldsA = lds;
  char* ldsB = lds + 128 * 64 * 2;
  int n0 = blockIdx.x * 128, m0 = blockIdx.y * 128;
  int tid = threadIdx.x, lane = tid & 63, wid = tid >> 6;
  int wr = wid >> 1, wc = wid & 1;
  f32x4 acc[4][4] = {};
  for (int k0 = 0; k0 < K; k0 += 64) {
    __syncthreads();
#pragma unroll
    for (int i = 0; i < 4; i++) {
      int idx = tid + i * 256;
      int row = idx >> 3, cb = idx & 7;
      uint4 va = *(const uint4*)(A + (size_t)(m0 + row) * K + k0 + cb * 8);
      *(uint4*)(ldsA + row * 128 + ((cb * 16) ^ ((row & 7) << 4))) = va;
      uint4 vb = *(const uint4*)(B + (size_t)(n0 + row) * K + k0 + cb * 8);
      *(uint4*)(ldsB + row * 128 + ((cb * 16) ^ ((row & 7) << 4))) = vb;
    }
    __syncthreads();
#pragma unroll
    for (int kk = 0; kk < 2; kk++) {
      bf16x8 af[4], bfr[4];
#pragma unroll
      for (int mt = 0; mt < 4; mt++) {
        int row = wr * 64 + mt * 16 + (lane & 15);
        int kb = kk * 64 + ((lane >> 4) << 4);
        af[mt] = *(const bf16x8*)(ldsA + row * 128 + (kb ^ ((row & 7) << 4)));
      }
#pragma unroll
      for (int nt = 0; nt < 4; nt++) {
        int row = wc * 64 + nt * 16 + (lane & 15);
        int kb = kk * 64 + ((lane >> 4) << 4);
        bfr[nt] = *(const bf16x8*)(ldsB + row * 128 + (kb ^ ((row & 7) << 4)));
      }
#pragma unroll
      for (int mt = 0; mt < 4; mt++)
#pragma unroll
        for (int nt = 0; nt < 4; nt++)
          acc[mt][nt] = __builtin_amdgcn_mfma_f32_16x16x32_bf16(af[mt], bfr[nt], acc[mt][nt], 0, 0, 0);
    }
  }
#pragma unroll
  for (int mt = 0; mt < 4; mt++)
#pragma unroll
    for (int nt = 0; nt < 4; nt++) {
      int row = m0 + wr * 64 + mt * 16 + ((lane >> 4) << 2);
      int col = n0 + wc * 64 + nt * 16 + (lane & 15);
#pragma unroll
      for (int r = 0; r < 4; r++)
        C[(size_t)(row + r) * N + col] = acc[mt][nt][r];
    }
}

// qkv [4096][1536] f32 -> Qp/Kp [8][4096][128] bf16, both [hi | lo].
// Q is pre-scaled by 8*log2(e) so QK^T lands directly in the exp2 domain.
__global__ void prep_qk_kernel(const float* __restrict__ qkv, u16* __restrict__ Qp, u16* __restrict__ Kp) {
  int i = blockIdx.x * 256 + threadIdx.x;  // 8*4096*64 = 2097152 exact
  int dh = i & 63;
  int n = (i >> 6) & 4095;
  int h = i >> 18;
  float q = qkv[(size_t)n * K3 + h * 64 + dh] * QSCALE;
  float k = qkv[(size_t)n * K3 + 512 + h * 64 + dh];
  u16 qhi = f2bf(q); u16 qlo = f2bf(q - bf2f(qhi));
  u16 khi = f2bf(k); u16 klo = f2bf(k - bf2f(khi));
  u16* qr = Qp + ((size_t)h * N_TOK + n) * 128;
  u16* kr = Kp + ((size_t)h * N_TOK + n) * 128;
  qr[dh] = qhi; qr[64 + dh] = qlo;
  kr[dh] = khi; kr[64 + dh] = klo;
}

// qkv V-part [4096][h*64] -> Vt [8][64][4096] bf16 (V^T per head, via LDS transpose)
__global__ __launch_bounds__(256) void prep_v_kernel(const float* __restrict__ qkv, u16* __restrict__ Vt) {
  __shared__ float lds[64][65];
  int n0 = blockIdx.x * 64, h = blockIdx.y;
  int tid = threadIdx.x;
#pragma unroll
  for (int i = 0; i < 4; i++) {
    int idx = tid + i * 256;
    int r = idx >> 4, s = idx & 15;
    const float4 v = *(const float4*)(qkv + (size_t)(n0 + r) * K3 + 1024 + h * 64 + s * 4);
    lds[r][s * 4 + 0] = v.x; lds[r][s * 4 + 1] = v.y;
    lds[r][s * 4 + 2] = v.z; lds[r][s * 4 + 3] = v.w;
  }
  __syncthreads();
  int dh = tid >> 2, ns = tid & 3;
  u16x8 pv[2];
#pragma unroll
  for (int half = 0; half < 2; half++)
#pragma unroll
    for (int j = 0; j < 8; j++)
      pv[half][j] = f2bf(lds[ns * 16 + half * 8 + j][dh]);
  u16* dst = Vt + ((size_t)h * 64 + dh) * N_TOK + n0 + ns * 16;
  *(u16x8*)(dst) = pv[0];
  *(u16x8*)(dst + 8) = pv[1];
}

// Flash attention, KV-split=2, swapped QK^T (S^T = mfma(K,Q)) for lane-local softmax.
// Block = (64 q-rows, head, kv-half); 4 waves x 16 q-rows; 32 kv tiles of 64.
// LDS: K 16KB @0; V 8KB @16384; P 8KB @24576 (per-wave). 2 barriers/iter.
__global__ __launch_bounds__(256) void attn_kernel(
    const u16* __restrict__ Qp, const u16* __restrict__ Kp,
    const u16* __restrict__ Vt, float* __restrict__ Uws,
    float* __restrict__ Mws, float* __restrict__ Lws) {
  __shared__ char lds[32768];
  char* ldsK = lds;              // [64 tok][128] bf16 = 256B rows, swizzled
  char* ldsV = lds + 16384;      // [64 dh][64 kv] bf16 = 128B rows, swizzled
  char* ldsP = lds + 24576;      // per-wave [16 q][64 kv] bf16
  int bid = blockIdx.x;
  int h = bid & 7;               // head -> XCD round-robin
  int rest = bid >> 3;           // 0..127
  int half = rest & 1;
  int q0 = (rest >> 1) * 64;
  int kvbase = half * 2048;
  int tid = threadIdx.x, lane = tid & 63, wid = tid >> 6;
  char* myP = ldsP + wid * 2048;
  int qcol = lane & 15;          // this lane's q (softmax layout)
  int g = lane >> 4;

  // Q fragments: row = [qhi(64) | qlo(64)]; qf[0..1]=hi c0,c1; qf[2..3]=lo c0,c1
  bf16x8 qf[4];
  {
    const u16* qrow = Qp + ((size_t)h * N_TOK + q0 + wid * 16 + qcol) * 128 + (g * 8);
#pragma unroll
    for (int c = 0; c < 4; c++) qf[c] = *(const bf16x8*)(qrow + c * 32);
  }
  const u16* Kbase = Kp + (size_t)h * N_TOK * 128;
  const u16* Vbase = Vt + (size_t)h * 64 * N_TOK;

  f32x4 o[4] = {};
  float mrow = -INFINITY, lrow = 0.f;  // per-lane scalars for q = qcol (log2 domain)

  for (int t = 0; t < 32; ++t) {
    int kv0 = kvbase + t * 64;
    __syncthreads();  // prior iter's LDS reads done
    // stage K tile: 64 rows x 256B
#pragma unroll
    for (int i = 0; i < 4; i++) {
      int idx = tid + i * 256, row = idx >> 4, cb = idx & 15;
      uint4 v = *(const uint4*)(Kbase + (size_t)(kv0 + row) * 128 + cb * 8);
      *(uint4*)(ldsK + row * 256 + ((cb * 16) ^ ((row & 7) << 4))) = v;
    }
    // stage V tile: 64 rows x 128B
#pragma unroll
    for (int i = 0; i < 2; i++) {
      int idx = tid + i * 256, row = idx >> 3, cb = idx & 7;
      uint4 v = *(const uint4*)(Vbase + (size_t)row * N_TOK + kv0 + cb * 8);
      *(uint4*)(ldsV + row * 128 + ((cb * 16) ^ ((row & 7) << 4))) = v;
    }
    __syncthreads();  // panels ready

    // S^T = mfma(K, Q): s[nt][r] = S[kv = nt*16 + g*4 + r][q = qcol], log2 domain.
    // Split precision: Khi*Qhi + Klo*Qhi + Khi*Qlo (scale pre-folded into Q).
    f32x4 s[4];
#pragma unroll
    for (int nt = 0; nt < 4; nt++) {
      int row = nt * 16 + qcol;
      const char* kb = ldsK + row * 256;
      int swz = (row & 7) << 4;
      int ko = g << 4;
      bf16x8 kf0 = *(const bf16x8*)(kb + ((ko) ^ swz));
      bf16x8 kf1 = *(const bf16x8*)(kb + ((64 + ko) ^ swz));
      bf16x8 kf2 = *(const bf16x8*)(kb + ((128 + ko) ^ swz));
      bf16x8 kf3 = *(const bf16x8*)(kb + ((192 + ko) ^ swz));
      f32x4 acc = {};
      acc = __builtin_amdgcn_mfma_f32_16x16x32_bf16(kf0, qf[0], acc, 0, 0, 0);
      acc = __builtin_amdgcn_mfma_f32_16x16x32_bf16(kf1, qf[1], acc, 0, 0, 0);
      acc = __builtin_amdgcn_mfma_f32_16x16x32_bf16(kf2, qf[0], acc, 0, 0, 0);
      acc = __builtin_amdgcn_mfma_f32_16x16x32_bf16(kf3, qf[1], acc, 0, 0, 0);
      acc = __builtin_amdgcn_mfma_f32_16x16x32_bf16(kf0, qf[2], acc, 0, 0, 0);
      acc = __builtin_amdgcn_mfma_f32_16x16x32_bf16(kf1, qf[3], acc, 0, 0, 0);
      s[nt] = acc;
    }

    // lane-local softmax for q = qcol: 16 values in-register, 2+2 shuffles total.
    float m = s[0][0];
#pragma unroll
    for (int nt = 0; nt < 4; nt++)
#pragma unroll
      for (int r = 0; r < 4; r++) m = fmaxf(m, s[nt][r]);
    m = fmaxf(m, __shfl_xor(m, 16));
    m = fmaxf(m, __shfl_xor(m, 32));
    float mnew = fmaxf(mrow, m);
    float alpha = exp2f(mrow - mnew);
    mrow = mnew;
    float psum = 0.f;
#pragma unroll
    for (int nt = 0; nt < 4; nt++)
#pragma unroll
      for (int r = 0; r < 4; r++) {
        float p = exp2f(s[nt][r] - mnew);
        s[nt][r] = p;
        psum += p;
      }
    psum += __shfl_xor(psum, 16);
    psum += __shfl_xor(psum, 32);
    lrow = lrow * alpha + psum;

    // rescale O: o's q index is (g*4 + r) -> fetch alpha from lane holding that q.
#pragma unroll
    for (int r = 0; r < 4; r++) {
      float a = __shfl(alpha, (g << 2) | r);
      o[0][r] *= a; o[1][r] *= a; o[2][r] *= a; o[3][r] *= a;
    }

    // P -> per-wave LDS (bf16): lane owns row q=qcol, kv = nt*16+g*4 .. +3 contiguous.
    // 4x ds_write_b64 (vs 16 scalar writes before).
#pragma unroll
    for (int nt = 0; nt < 4; nt++) {
      u16 h0 = f2bf(s[nt][0]), h1 = f2bf(s[nt][1]);
      u16 h2 = f2bf(s[nt][2]), h3 = f2bf(s[nt][3]);
      u32 w0 = (u32)h0 | ((u32)h1 << 16);
      u32 w1 = (u32)h2 | ((u32)h3 << 16);
      int off = (nt * 32 + g * 8) ^ ((qcol & 7) << 4);
      *(uint2*)(myP + qcol * 128 + off) = make_uint2(w0, w1);
    }
    // No barrier: myP is wave-private; same-wave LDS ordering via lgkmcnt.

    // O += P . V  (orientation unchanged from proven rounds)
#pragma unroll
    for (int c = 0; c < 2; c++) {
      int prow = lane & 15;
      int kb2 = c * 64 + (g << 4);
      bf16x8 pf = *(const bf16x8*)(myP + prow * 128 + (kb2 ^ ((prow & 7) << 4)));
#pragma unroll
      for (int nt = 0; nt < 4; nt++) {
        int vrow = nt * 16 + (lane & 15);
        bf16x8 vf = *(const bf16x8*)(ldsV + vrow * 128 + (kb2 ^ ((vrow & 7) << 4)));
        o[nt] = __builtin_amdgcn_mfma_f32_16x16x32_bf16(pf, vf, o[nt], 0, 0, 0);
      }
    }
  }

  // epilogue: write unnormalized U (f32). o[nt][r] belongs to q = g*4+r,
  // dh = nt*16 + (lane&15).
  size_t base = ((size_t)(half * HEADS + h) * N_TOK);
#pragma unroll
  for (int r = 0; r < 4; r++) {
    int tok = q0 + wid * 16 + (g << 2) + r;
    float* urow = Uws + (base + tok) * 64;
#pragma unroll
    for (int nt = 0; nt < 4; nt++)
      urow[nt * 16 + (lane & 15)] = o[nt][r];
  }
  // M/L: lane holds m/l for q = qcol; single writer per token (g==0 lanes).
  if (g == 0) {
    int tok = q0 + wid * 16 + qcol;
    Mws[base + tok] = mrow;
    Lws[base + tok] = lrow;
  }
}

// Combine the two KV-halves (log2 domain): w_i = exp2(m_i - m)
__global__ void reduce_kernel(const float* __restrict__ Uws, const float* __restrict__ Mws,
                              const float* __restrict__ Lws, u16* __restrict__ Obuf) {
  int i = blockIdx.x * 256 + threadIdx.x;  // 8*4096*16 = 524288 exact
  int d4 = i & 15;
  int tok = (i >> 4) & 4095;
  int h = i >> 16;
  size_t b1 = (size_t)h * N_TOK + tok;
  size_t b2 = (size_t)(HEADS + h) * N_TOK + tok;
  float m1 = Mws[b1], m2 = Mws[b2];
  float l1 = Lws[b1], l2 = Lws[b2];
  float m = fmaxf(m1, m2);
  float w1 = exp2f(m1 - m), w2 = exp2f(m2 - m);
  float inv = 1.0f / (l1 * w1 + l2 * w2);
  f32x4 u1 = *(const f32x4*)(Uws + b1 * 64 + d4 * 4);
  f32x4 u2 = *(const f32x4*)(Uws + b2 * 64 + d4 * 4);
  u16* dst = Obuf + (size_t)tok * C_DIM + h * 64 + d4 * 4;
#pragma unroll
  for (int j = 0; j < 4; j++)
    dst[j] = f2bf((u1[j] * w1 + u2[j] * w2) * inv);
}

extern "C" void kernel_launch(void* const* d_in, const int* in_sizes, int n_in,
                              void* d_out, int out_size, void* d_ws, size_t ws_size,
                              hipStream_t stream) {
  const float* x = (const float*)d_in[0];      // [512][4096]
  const float* w_qkv = (const float*)d_in[1];  // [1536][512]
  const float* w_out = (const float*)d_in[2];  // [512][512]
  float* out = (float*)d_out;                  // [512][4096]
  char* ws = (char*)d_ws;
  // Workspace (59,768,832 B total, proven available). Overlays:
  //   Obuf overlays B1; Vt overlays A1; U/M/L overlay qkv (all dead by then).
  size_t off = 0;
  size_t off_B1 = off;  off += (size_t)N_TOK * K3 * 2;          // 12,582,912
  size_t off_A1 = off;  off += (size_t)K3 * K3 * 2;             //  4,718,592
  size_t off_A2 = off;  off += (size_t)512 * 512 * 2;           //    524,288
  size_t off_qkv = off; off += (size_t)N_TOK * K3 * 4;          // 25,165,824
  size_t off_Qp = off;  off += (size_t)HEADS * N_TOK * 128 * 2; //  8,388,608
  size_t off_Kp = off;  off += (size_t)HEADS * N_TOK * 128 * 2; //  8,388,608
  u16* B1 = (u16*)(ws + off_B1);
  u16* A1 = (u16*)(ws + off_A1);
  u16* A2 = (u16*)(ws + off_A2);
  float* qkv = (float*)(ws + off_qkv);
  u16* Qp = (u16*)(ws + off_Qp);
  u16* Kp = (u16*)(ws + off_Kp);
  u16* Vt = (u16*)(ws + off_A1);     // overlay A1 (4,194,304 <= 4,718,592)
  u16* Obuf = (u16*)(ws + off_B1);   // overlay B1 (4,194,304 <= 12,582,912)
  float* Uws = (float*)(ws + off_qkv);                       // 16,777,216
  float* Mws = (float*)(ws + off_qkv + 16777216);            //    262,144
  float* Lws = (float*)(ws + off_qkv + 16777216 + 262144);   //    262,144

  prep_w_kernel<<<(1536 * 512 + 255) / 256, 256, 0, stream>>>(w_qkv, A1);
  prep_wout_kernel<<<(512 * 512 + 255) / 256, 256, 0, stream>>>(w_out, A2);
  prep_x_kernel<<<dim3(64, 8), 256, 0, stream>>>(x, B1);
  gemm_nt_kernel<<<dim3(K3 / 128, N_TOK / 128), 256, 0, stream>>>(B1, A1, qkv, N_TOK, K3, K3);
  prep_qk_kernel<<<(HEADS * N_TOK * 64) / 256, 256, 0, stream>>>(qkv, Qp, Kp);
  prep_v_kernel<<<dim3(64, 8), 256, 0, stream>>>(qkv, Vt);
  attn_kernel<<<1024, 256, 0, stream>>>(Qp, Kp, Vt, Uws, Mws, Lws);
  reduce_kernel<<<(HEADS * N_TOK * 16) / 256, 256, 0, stream>>>(Uws, Mws, Lws, Obuf);
  gemm_nt_kernel<<<dim3(N_TOK / 128, 512 / 128), 256, 0, stream>>>(A2, Obuf, out, 512, N_TOK, 512);
}